// Round 6
// baseline (186.075 us; speedup 1.0000x reference)
//
#include <hip/hip_runtime.h>
#include <hip/hip_bf16.h>

// Problem constants: B=16, N=1024, D=768 -> T=16384 tokens.
#define T_TOK   16384
#define D_DIM   768
#define ROWB    1536          // bytes per row (768 * 2B bf16)
#define INV_TEMP (1.0f/0.07f)
#define XROWS   17152
#define XALL_BYTES (XROWS * ROWB)

typedef __bf16 bf16x8 __attribute__((ext_vector_type(8)));
typedef float  f32x4  __attribute__((ext_vector_type(4)));
typedef unsigned int u32;

__device__ __forceinline__ u32 f2u(float f) {
    u32 b = __float_as_uint(f);
    return (b & 0x80000000u) ? ~b : (b | 0x80000000u);
}
__device__ __forceinline__ float u2f(u32 u) {
    u32 b = (u & 0x80000000u) ? (u & 0x7FFFFFFFu) : ~u;
    return __uint_as_float(b);
}

__device__ __forceinline__ void gload16(const void* g, void* l) {
    __builtin_amdgcn_global_load_lds((const __attribute__((address_space(1))) u32*)g,
                                     (__attribute__((address_space(3))) u32*)l,
                                     16, 0, 0);
}

// ============================================================================
// K1: class-wise prefix scan. meta[0]=R, meta[1]=F, meta[2]=Rpad(256-aligned).
// ============================================================================
__global__ void k_scan(const int* __restrict__ labels, int* __restrict__ pos,
                       int* __restrict__ meta)
{
    __shared__ int sr[256], sf[256];
    const int t = threadIdx.x;
    const int base = t * 64;
    int cr = 0, cf = 0;
    for (int i = 0; i < 64; ++i) {
        int v = labels[base + i];
        cr += (v == 0);
        cf += (v == 1);
    }
    sr[t] = cr; sf[t] = cf;
    __syncthreads();
    if (t == 0) {
        int ar = 0, af = 0;
        for (int i = 0; i < 256; ++i) {
            int r = sr[i]; sr[i] = ar; ar += r;
            int f = sf[i]; sf[i] = af; af += f;
        }
        meta[0] = ar;
        meta[1] = af;
        meta[2] = (ar + 255) & ~255;
    }
    __syncthreads();
    int pr = sr[t], pf = sf[t];
    for (int i = 0; i < 64; ++i) {
        int v = labels[base + i];
        pos[base + i] = (v == 0) ? pr++ : pf++;
    }
}

// ============================================================================
// K2: L2-normalize rows, bf16-convert, scatter compacted by class.
// ============================================================================
__global__ void k_norm(const float* __restrict__ x, const int* __restrict__ labels,
                       const int* __restrict__ pos, const int* __restrict__ meta,
                       __hip_bfloat16* __restrict__ Xall)
{
    const int row = blockIdx.x;
    const int t = threadIdx.x;
    const float* xr = x + (size_t)row * D_DIM;
    float a0 = xr[t], a1 = xr[t + 256], a2 = xr[t + 512];
    float ss = a0 * a0 + a1 * a1 + a2 * a2;
    #pragma unroll
    for (int m = 32; m >= 1; m >>= 1) ss += __shfl_xor(ss, m);
    __shared__ float sred[4];
    if ((t & 63) == 0) sred[t >> 6] = ss;
    __syncthreads();
    float tot = sred[0] + sred[1] + sred[2] + sred[3];
    float inv = 1.0f / fmaxf(sqrtf(tot), 1e-12f);
    int lab = labels[row];
    int base = (lab == 0) ? pos[row] : (meta[2] + pos[row]);
    __hip_bfloat16* dst = Xall + (size_t)base * D_DIM;
    dst[t]       = __float2bfloat16(a0 * inv);
    dst[t + 256] = __float2bfloat16(a1 * inv);
    dst[t + 512] = __float2bfloat16(a2 * inv);
}

// ============================================================================
// K3: streaming 256x256 tiles, 8-phase, register-resident operands.
// Round 6: EXACT work distribution. Grid = 256 blocks (1/CU). Work = (bm,grp)
// pairs, P = nbm*min(8,nbn); common case (R~8192) P == 256 -> every block
// active, one prologue, no stragglers. XCD-clustered bijective decode when
// nbm==32 (each XCD owns 4 A-panels, 1.5 MB -> L2-resident); generic
// decode otherwise. Grid-stride p-loop with vmcnt(0) drain between streams
// (prevents cross-stream gload_lds write-write races in LDS).
// Schedule per K-tile (24 ds_read_b128/wave, minimum) unchanged from r5.
// ============================================================================
#define MFMA16(a,b,c) __builtin_amdgcn_mfma_f32_16x16x32_bf16(a,b,c,0,0,0)

#define LA(buf,mq) (lds + (buf)*65536 + (mq)*16384)
#define LB(buf,nq) (lds + (buf)*65536 + 32768 + (nq)*16384)

// step s -> (bi = s/12, kt = s%12); wave-uniform scalar math.
#define STAGE_A(buf,mq,s) do { \
    int kt_ = (s) - ((s)/12)*12; \
    gload16(sA0[mq] + kt_*128, LA(buf,mq) + wq); \
    gload16(sA1[mq] + kt_*128, LA(buf,mq) + wq + 8192); } while(0)
#define STAGE_B(buf,nq,s) do { \
    int bi_ = (s)/12, kt_ = (s) - bi_*12; \
    const char* bp_ = Bb + (size_t)(grp + Gm*bi_) * (256*ROWB); \
    gload16(bp_ + boff0[nq] + kt_*128, LB(buf,nq) + wq); \
    gload16(bp_ + boff1[nq] + kt_*128, LB(buf,nq) + wq + 8192); } while(0)

#define BAR    __builtin_amdgcn_s_barrier()
#define GUARD8 asm volatile("s_waitcnt vmcnt(8)\n\ts_barrier" ::: "memory")
#define DRAIN0 asm volatile("s_waitcnt vmcnt(0)\n\ts_barrier" ::: "memory")

#define LOAD_A(buf,mq) do { \
    _Pragma("unroll") \
    for (int mm = 0; mm < 4; ++mm) { \
        afr[mm][0] = *(const bf16x8*)(LA(buf,mq) + aBase + mm*2048 + cb0); \
        afr[mm][1] = *(const bf16x8*)(LA(buf,mq) + aBase + mm*2048 + cb1); } } while(0)
#define LOAD_B(buf,nq,dst) do { \
    _Pragma("unroll") \
    for (int nn = 0; nn < 2; ++nn) { \
        dst[nn][0] = *(const bf16x8*)(LB(buf,nq) + bBase + nn*2048 + cb0); \
        dst[nn][1] = *(const bf16x8*)(LB(buf,nq) + bBase + nn*2048 + cb1); } } while(0)

// barrier -> MFMA cluster (16 mfma) for quadrant (mq,nq) using bvx registers.
#define MM(mq,nq,bvx) do { \
    __builtin_amdgcn_s_barrier(); \
    __builtin_amdgcn_s_setprio(1); \
    _Pragma("unroll") \
    for (int mm = 0; mm < 4; ++mm) { \
        _Pragma("unroll") \
        for (int nn = 0; nn < 2; ++nn) { \
            acc[(mq)*4+mm][(nq)*2+nn] = MFMA16(afr[mm][0], bvx[nn][0], acc[(mq)*4+mm][(nq)*2+nn]); \
            acc[(mq)*4+mm][(nq)*2+nn] = MFMA16(afr[mm][1], bvx[nn][1], acc[(mq)*4+mm][(nq)*2+nn]); } } \
    __builtin_amdgcn_s_setprio(0); \
} while(0)

__global__ __launch_bounds__(512, 2) void k_gemm(const __hip_bfloat16* __restrict__ Xall,
                                                 const int* __restrict__ meta,
                                                 u32* __restrict__ rowmax,
                                                 u32* __restrict__ colmax)
{
    const int R = meta[0], Fc = meta[1], Rpad = meta[2];
    const int nbm = (R + 255) >> 8;
    const int nbn = (Fc + 255) >> 8;
    if (nbm == 0 || nbn == 0) return;
    const int Gm = (nbn < 8) ? nbn : 8;
    const int P  = nbm * Gm;
    const int lin = blockIdx.x;

    __shared__ __align__(16) char lds[131072];

    const int tid = threadIdx.x;
    const int w  = tid >> 6, l = tid & 63;
    const int wm = w >> 2, wn = w & 3;
    const int lg = l >> 4, li = l & 15;
    const int wq = w * 1024;

    const int row0 = w * 8 + (l >> 3);
    const int ch   = ((l & 7) ^ (row0 & 7)) * 16;
    const int brow = ((row0 >> 5) << 6) + (row0 & 31);

    const char* Bb = (const char*)Xall + (size_t)Rpad * ROWB;

    int boff0[2], boff1[2];
    #pragma unroll
    for (int q = 0; q < 2; ++q) {
        boff0[q] = (q * 32 + brow) * ROWB + ch;
        boff1[q] = (128 + q * 32 + brow) * ROWB + ch;
    }

    const int aBase = (wm * 64 + li) * 128;
    const int bBase = (wn * 32 + li) * 128;
    const int sw  = li & 7;
    const int cb0 = (lg ^ sw) * 16;
    const int cb1 = ((4 + lg) ^ sw) * 16;

    const float MASKED = -3.0f;
    f32x4 acc[8][4];
    #pragma unroll
    for (int m = 0; m < 8; ++m)
        #pragma unroll
        for (int n = 0; n < 4; ++n)
            acc[m][n] = (f32x4){0.f, 0.f, 0.f, 0.f};

    bf16x8 afr[4][2], bv0[2][2], bv1[2][2];

    #pragma unroll 1
    for (int p = lin; p < P; p += 256) {
        // ---- decode (bm, grp); XCD-clustered when nbm==32 (common case) ----
        int bm, grp;
        if (nbm == 32 && Gm == 8) {
            int xcd = p & 7, i = p >> 3;
            bm = ((i & 3) << 3) + xcd;      // XCD x owns bm in {x,8+x,16+x,24+x}
            grp = i >> 2;
        } else {
            bm = p % nbm; grp = p / nbm;
        }
        const int nt = (nbn - grp + Gm - 1) / Gm;
        const int NS = 12 * nt;

        const char* Ab = (const char*)Xall + (size_t)(bm * 256) * ROWB;
        const char* sA0[2]; const char* sA1[2];
        #pragma unroll
        for (int q = 0; q < 2; ++q) {
            sA0[q] = Ab + (size_t)(q * 64 + row0) * ROWB + ch;
            sA1[q] = Ab + (size_t)(128 + q * 64 + row0) * ROWB + ch;
        }

        // drain any previous stream's in-flight LDS writes (no-op on first p)
        DRAIN0;

        // prologue: tile0 -> buf0 (oldest 8), tile1 -> buf1 (next 8)
        STAGE_A(0,0,0); STAGE_B(0,0,0); STAGE_B(0,1,0); STAGE_A(0,1,0);
        STAGE_A(1,0,1); STAGE_B(1,0,1); STAGE_B(1,1,1); STAGE_A(1,1,1);
        GUARD8;   // tile0 arrived; tile1's 8 may fly (forced by end-ph3 guard)

        for (int bi = 0; bi < nt; ++bi) {
            #pragma unroll 1
            for (int j = 0; j < 6; ++j) {
                const int it = bi * 6 + j;
                int sA = 2 * it + 2; if (sA > NS - 1) sA = NS - 1;
                int sB = 2 * it + 3; if (sB > NS - 1) sB = NS - 1;

                // ---- buf0: tile 2it ----
                LOAD_A(0,0); LOAD_B(0,0,bv0);
                MM(0,0,bv0);
                BAR;
                LOAD_B(0,1,bv1);
                STAGE_A(0,0,sA); STAGE_B(0,0,sA);
                MM(0,1,bv1);
                BAR;
                LOAD_A(0,1);
                STAGE_B(0,1,sA);
                MM(1,1,bv1);
                BAR;
                STAGE_A(0,1,sA);
                MM(1,0,bv0);
                GUARD8;   // buf1 tile 2it+1 fully arrived
                // ---- buf1: tile 2it+1 ----
                LOAD_A(1,0); LOAD_B(1,0,bv0);
                MM(0,0,bv0);
                BAR;
                LOAD_B(1,1,bv1);
                STAGE_A(1,0,sB); STAGE_B(1,0,sB);
                MM(0,1,bv1);
                BAR;
                LOAD_A(1,1);
                STAGE_B(1,1,sB);
                MM(1,1,bv1);
                BAR;
                STAGE_A(1,1,sB);
                MM(1,0,bv0);
                GUARD8;   // buf0 tile 2it+2 fully arrived
            }

            // ---- per-bn register epilogue (no barriers; overlaps prefetch) --
            const int bnv = grp + Gm * bi;
            // rowmax flush (reduce over n + li-group, then atomic)
            #pragma unroll
            for (int m = 0; m < 8; ++m)
                #pragma unroll
                for (int reg = 0; reg < 4; ++reg) {
                    float v = MASKED;
                    #pragma unroll
                    for (int n = 0; n < 4; ++n) {
                        int gc = bnv * 256 + wn * 64 + n * 16 + li;
                        v = fmaxf(v, (gc < Fc) ? acc[m][n][reg] : MASKED);
                    }
                    v = fmaxf(v, __shfl_xor(v, 1));
                    v = fmaxf(v, __shfl_xor(v, 2));
                    v = fmaxf(v, __shfl_xor(v, 4));
                    v = fmaxf(v, __shfl_xor(v, 8));
                    int gr = bm * 256 + wm * 128 + m * 16 + lg * 4 + reg;
                    if (li == 0 && gr < R) atomicMax(&rowmax[gr], f2u(v));
                }
            // colmax flush (mask rows >= R)
            #pragma unroll
            for (int n = 0; n < 4; ++n) {
                float v = MASKED;
                #pragma unroll
                for (int m = 0; m < 8; ++m)
                    #pragma unroll
                    for (int reg = 0; reg < 4; ++reg) {
                        int gr = bm * 256 + wm * 128 + m * 16 + lg * 4 + reg;
                        v = fmaxf(v, (gr < R) ? acc[m][n][reg] : MASKED);
                    }
                v = fmaxf(v, __shfl_xor(v, 16));
                v = fmaxf(v, __shfl_xor(v, 32));
                int gc = bnv * 256 + wn * 64 + n * 16 + li;
                if (lg == 0 && gc < Fc) atomicMax(&colmax[gc], f2u(v));
            }
            // reset acc
            #pragma unroll
            for (int m = 0; m < 8; ++m)
                #pragma unroll
                for (int n = 0; n < 4; ++n)
                    acc[m][n] = (f32x4){0.f, 0.f, 0.f, 0.f};
        }
    }
}

// ============================================================================
// K4: maxes -> loss, masked means, scalar out.
// ============================================================================
__global__ void k_final(const u32* __restrict__ rowmax, const u32* __restrict__ colmax,
                        const int* __restrict__ meta, float* __restrict__ out)
{
    const int R = meta[0], Fc = meta[1];
    const int t = threadIdx.x;
    float sr = 0.f, sf = 0.f;
    for (int i = t; i < R; i += 256) {
        u32 u = rowmax[i];
        float m = (u == 0u) ? -1e9f : u2f(u) * INV_TEMP;
        float sg = 1.0f / (1.0f + expf(-m));
        sr += -logf(1.0f - sg + 1e-6f);
    }
    for (int i = t; i < Fc; i += 256) {
        u32 u = colmax[i];
        float m = (u == 0u) ? -1e9f : u2f(u) * INV_TEMP;
        float sg = 1.0f / (1.0f + expf(-m));
        sf += -logf(1.0f - sg + 1e-6f);
    }
    #pragma unroll
    for (int msk = 32; msk >= 1; msk >>= 1) {
        sr += __shfl_xor(sr, msk);
        sf += __shfl_xor(sf, msk);
    }
    __shared__ float r4[4], f4[4];
    if ((t & 63) == 0) { r4[t >> 6] = sr; f4[t >> 6] = sf; }
    __syncthreads();
    if (t == 0) {
        float a = (r4[0] + r4[1] + r4[2] + r4[3]) / (float)((R > 0) ? R : 1);
        float b = (f4[0] + f4[1] + f4[2] + f4[3]) / (float)((Fc > 0) ? Fc : 1);
        out[0] = 0.5f * (a + b);
    }
}

// ============================================================================
extern "C" void kernel_launch(void* const* d_in, const int* in_sizes, int n_in,
                              void* d_out, int out_size, void* d_ws, size_t ws_size,
                              hipStream_t stream)
{
    (void)in_sizes; (void)n_in; (void)out_size; (void)ws_size;
    const float* x    = (const float*)d_in[0];
    const int* labels = (const int*)d_in[1];
    float* out        = (float*)d_out;

    char* ws = (char*)d_ws;
    int* meta = (int*)ws;
    int* pos  = (int*)(ws + 256);
    __hip_bfloat16* Xall = (__hip_bfloat16*)(ws + 131072);
    u32* rowmax = (u32*)(ws + 131072 + XALL_BYTES);
    u32* colmax = rowmax + 16384;

    k_scan<<<1, 256, 0, stream>>>(labels, pos, meta);
    k_norm<<<T_TOK, 256, 0, stream>>>(x, labels, pos, meta, Xall);
    hipMemsetAsync(rowmax, 0, 2 * 16384 * sizeof(u32), stream);
    k_gemm<<<256, 512, 0, stream>>>(Xall, meta, rowmax, colmax);
    k_final<<<1, 256, 0, stream>>>(rowmax, colmax, meta, out);
}

// Round 7
// 174.490 us; speedup vs baseline: 1.0664x; 1.0664x over previous
//
#include <hip/hip_runtime.h>
#include <hip/hip_bf16.h>

// Problem constants: B=16, N=1024, D=768 -> T=16384 tokens.
#define T_TOK   16384
#define D_DIM   768
#define ROWB    1536          // bytes per row (768 * 2B bf16)
#define INV_TEMP (1.0f/0.07f)
#define XROWS   17152
#define XALL_BYTES (XROWS * ROWB)

typedef __bf16 bf16x8 __attribute__((ext_vector_type(8)));
typedef float  f32x4  __attribute__((ext_vector_type(4)));
typedef unsigned int u32;

__device__ __forceinline__ u32 f2u(float f) {
    u32 b = __float_as_uint(f);
    return (b & 0x80000000u) ? ~b : (b | 0x80000000u);
}
__device__ __forceinline__ float u2f(u32 u) {
    u32 b = (u & 0x80000000u) ? (u & 0x7FFFFFFFu) : ~u;
    return __uint_as_float(b);
}

__device__ __forceinline__ void gload16(const void* g, void* l) {
    __builtin_amdgcn_global_load_lds((const __attribute__((address_space(1))) u32*)g,
                                     (__attribute__((address_space(3))) u32*)l,
                                     16, 0, 0);
}

// ============================================================================
// K1: class-wise prefix scan. meta[0]=R, meta[1]=F, meta[2]=Rpad(256-aligned).
// ============================================================================
__global__ void k_scan(const int* __restrict__ labels, int* __restrict__ pos,
                       int* __restrict__ meta)
{
    __shared__ int sr[256], sf[256];
    const int t = threadIdx.x;
    const int base = t * 64;
    int cr = 0, cf = 0;
    for (int i = 0; i < 64; ++i) {
        int v = labels[base + i];
        cr += (v == 0);
        cf += (v == 1);
    }
    sr[t] = cr; sf[t] = cf;
    __syncthreads();
    if (t == 0) {
        int ar = 0, af = 0;
        for (int i = 0; i < 256; ++i) {
            int r = sr[i]; sr[i] = ar; ar += r;
            int f = sf[i]; sf[i] = af; af += f;
        }
        meta[0] = ar;
        meta[1] = af;
        meta[2] = (ar + 255) & ~255;
    }
    __syncthreads();
    int pr = sr[t], pf = sf[t];
    for (int i = 0; i < 64; ++i) {
        int v = labels[base + i];
        pos[base + i] = (v == 0) ? pr++ : pf++;
    }
}

// ============================================================================
// K2: L2-normalize rows, bf16-convert, scatter compacted by class.
// ============================================================================
__global__ void k_norm(const float* __restrict__ x, const int* __restrict__ labels,
                       const int* __restrict__ pos, const int* __restrict__ meta,
                       __hip_bfloat16* __restrict__ Xall)
{
    const int row = blockIdx.x;
    const int t = threadIdx.x;
    const float* xr = x + (size_t)row * D_DIM;
    float a0 = xr[t], a1 = xr[t + 256], a2 = xr[t + 512];
    float ss = a0 * a0 + a1 * a1 + a2 * a2;
    #pragma unroll
    for (int m = 32; m >= 1; m >>= 1) ss += __shfl_xor(ss, m);
    __shared__ float sred[4];
    if ((t & 63) == 0) sred[t >> 6] = ss;
    __syncthreads();
    float tot = sred[0] + sred[1] + sred[2] + sred[3];
    float inv = 1.0f / fmaxf(sqrtf(tot), 1e-12f);
    int lab = labels[row];
    int base = (lab == 0) ? pos[row] : (meta[2] + pos[row]);
    __hip_bfloat16* dst = Xall + (size_t)base * D_DIM;
    dst[t]       = __float2bfloat16(a0 * inv);
    dst[t + 256] = __float2bfloat16(a1 * inv);
    dst[t + 512] = __float2bfloat16(a2 * inv);
}

// ============================================================================
// K3 (round 7): 128x128 tiles, 4 waves (2x2, per-wave 64x64), 64 KiB LDS ->
// TWO independent blocks per CU. Cross-block TLP fills the pipes during each
// block's barrier/guard stalls (m97/m114 mechanism) -- attacks the measured
// latency-bound regime (all pipes <40%).
// Per K-tile (BK=64): phA{LOAD_A 8 + LOAD_B0 4 reads; STAGE_B(t+1) 4; bar;
// 16 MFMA}, phB{LOAD_B1 4 reads; bar; 16 MFMA; STAGE_A(t+2) 4; GUARD4}.
// GUARD4 (FIFO vmcnt): outstanding at guard = A(t+2)4 | B(t+1)4 | A(t+1)4;
// vmcnt(4) forces A(t+1),B(t+1) complete -- strict, no timing luck.
// Stage-vs-read race safety: STAGE_B(t+1) targets buf^1 (not read this tile);
// STAGE_A(t+2) issued after phB's barrier (all waves' A reads of this buf
// completed at phA-MFMA which precedes that barrier).
// Streaming: block owns (bm,grp), iterates bn = grp+8k -> 96-K-tile stream,
// pipeline never drains across bn. XCD decode: bm == xcd (mod 8).
// ============================================================================
#define MFMA16(a,b,c) __builtin_amdgcn_mfma_f32_16x16x32_bf16(a,b,c,0,0,0)

#define LA(b)  (lds + (b)*32768)
#define LBr(b) (lds + (b)*32768 + 16384)

// step s -> (bi=s/12, kt=s%12); wave-uniform scalar math.
#define STAGE_A(b,s) do { \
    int kt_ = (s) % 12; \
    const char* ap_ = Ab + aoff + kt_*128; \
    gload16(ap_,           LA(b) + wq); \
    gload16(ap_ +  49152,  LA(b) + wq + 4096); \
    gload16(ap_ +  98304,  LA(b) + wq + 8192); \
    gload16(ap_ + 147456,  LA(b) + wq + 12288); } while(0)
#define STAGE_B(b,s) do { \
    int bi_ = (s)/12, kt_ = (s)%12; \
    const char* bp_ = Bb + (size_t)(grp + Gm*bi_) * (128*ROWB) + aoff + kt_*128; \
    gload16(bp_,           LBr(b) + wq); \
    gload16(bp_ +  49152,  LBr(b) + wq + 4096); \
    gload16(bp_ +  98304,  LBr(b) + wq + 8192); \
    gload16(bp_ + 147456,  LBr(b) + wq + 12288); } while(0)

#define GUARD4 asm volatile("s_waitcnt vmcnt(4)\n\ts_barrier" ::: "memory")
#define DRAIN0 asm volatile("s_waitcnt vmcnt(0)\n\ts_barrier" ::: "memory")

#define LOAD_A(b) do { \
    _Pragma("unroll") \
    for (int mm = 0; mm < 4; ++mm) { \
        afr[mm][0] = *(const bf16x8*)(LA(b) + aBase + mm*2048 + cb0); \
        afr[mm][1] = *(const bf16x8*)(LA(b) + aBase + mm*2048 + cb1); } } while(0)
#define LOAD_B0(b) do { \
    _Pragma("unroll") \
    for (int nn = 0; nn < 2; ++nn) { \
        bfrA[nn][0] = *(const bf16x8*)(LBr(b) + bBase + nn*2048 + cb0); \
        bfrA[nn][1] = *(const bf16x8*)(LBr(b) + bBase + nn*2048 + cb1); } } while(0)
#define LOAD_B1(b) do { \
    _Pragma("unroll") \
    for (int nn = 0; nn < 2; ++nn) { \
        bfrB[nn][0] = *(const bf16x8*)(LBr(b) + bBase + (2+nn)*2048 + cb0); \
        bfrB[nn][1] = *(const bf16x8*)(LBr(b) + bBase + (2+nn)*2048 + cb1); } } while(0)

#define MM(nbase,bvx) do { \
    __builtin_amdgcn_s_barrier(); \
    __builtin_amdgcn_s_setprio(1); \
    _Pragma("unroll") \
    for (int mm = 0; mm < 4; ++mm) { \
        _Pragma("unroll") \
        for (int nn = 0; nn < 2; ++nn) { \
            acc[mm][(nbase)+nn] = MFMA16(afr[mm][0], bvx[nn][0], acc[mm][(nbase)+nn]); \
            acc[mm][(nbase)+nn] = MFMA16(afr[mm][1], bvx[nn][1], acc[mm][(nbase)+nn]); } } \
    __builtin_amdgcn_s_setprio(0); \
} while(0)

#define TILE(b,t) do { \
    int sB_ = (t)+1; if (sB_ > NS-1) sB_ = NS-1; \
    int sA_ = (t)+2; if (sA_ > NS-1) sA_ = NS-1; \
    LOAD_A(b); LOAD_B0(b); \
    STAGE_B((b)^1, sB_); \
    MM(0, bfrA); \
    LOAD_B1(b); \
    MM(2, bfrB); \
    STAGE_A(b, sA_); \
    GUARD4; \
} while(0)

__global__ __launch_bounds__(256, 2) void k_gemm(const __hip_bfloat16* __restrict__ Xall,
                                                 const int* __restrict__ meta,
                                                 u32* __restrict__ rowmax,
                                                 u32* __restrict__ colmax)
{
    const int R = meta[0], Fc = meta[1], Rpad = meta[2];
    const int nbm = (R + 127) >> 7;
    const int nbn = (Fc + 127) >> 7;
    if (nbm == 0 || nbn == 0) return;
    const int Gm = (nbn < 8) ? nbn : 8;
    const int P  = nbm * Gm;

    __shared__ __align__(16) char lds[65536];

    const int tid = threadIdx.x;
    const int w  = tid >> 6, l = tid & 63;
    const int wm = w >> 1, wn = w & 1;
    const int lg = l >> 4, li = l & 15;
    const int wq = w * 1024;

    // staging geometry: thread covers row (tid>>3) + i*32, chunk (tid&7)^(row&7)
    const int srow = tid >> 3;
    const int ch   = ((tid & 7) ^ (srow & 7)) * 16;
    const int aoff = srow * ROWB + ch;

    const char* Bb = (const char*)Xall + (size_t)Rpad * ROWB;

    // MFMA read geometry
    const int aBase = (wm * 64 + li) * 128;
    const int bBase = (wn * 64 + li) * 128;
    const int sw  = li & 7;
    const int cb0 = (lg ^ sw) * 16;
    const int cb1 = ((4 + lg) ^ sw) * 16;

    const float MASKED = -3.0f;
    f32x4 acc[4][4];
    #pragma unroll
    for (int m = 0; m < 4; ++m)
        #pragma unroll
        for (int n = 0; n < 4; ++n)
            acc[m][n] = (f32x4){0.f, 0.f, 0.f, 0.f};

    bf16x8 afr[4][2], bfrA[2][2], bfrB[2][2];

    #pragma unroll 1
    for (int p = blockIdx.x; p < P; p += 512) {
        // ---- decode (bm, grp); XCD-clustered in the common case ----
        int bm, grp;
        if (nbm == 64 && Gm == 8) {
            int xcd = p & 7, i = p >> 3;
            bm = ((i & 7) << 3) + xcd;   // XCD x owns bm == x (mod 8)
            grp = i >> 3;
        } else {
            bm = p % nbm; grp = p / nbm;
        }
        const int nt = (nbn - grp + Gm - 1) / Gm;
        const int NS = 12 * nt;

        const char* Ab = (const char*)Xall + (size_t)(bm * 128) * ROWB;

        // drain any previous stream's in-flight LDS writes (no-op first pass)
        DRAIN0;

        // prologue: tile0 A+B -> buf0, tile1 A -> buf1 (B(1) staged in tile0)
        STAGE_A(0, 0); STAGE_B(0, 0);
        STAGE_A(1, (NS > 1) ? 1 : 0);
        GUARD4;   // forces A(0),B(0); leaves A(1) in flight

        #pragma unroll 1
        for (int th = 0; th < NS; th += 2) {
            TILE(0, th);
            TILE(1, th + 1);

            if (((th + 1) % 12) == 11) {
                // ---- per-bn register epilogue (no barriers) ----
                const int bnv = grp + Gm * ((th + 1) / 12);
                #pragma unroll
                for (int m = 0; m < 4; ++m)
                    #pragma unroll
                    for (int reg = 0; reg < 4; ++reg) {
                        float v = MASKED;
                        #pragma unroll
                        for (int n = 0; n < 4; ++n) {
                            int gc = bnv * 128 + wn * 64 + n * 16 + li;
                            v = fmaxf(v, (gc < Fc) ? acc[m][n][reg] : MASKED);
                        }
                        v = fmaxf(v, __shfl_xor(v, 1));
                        v = fmaxf(v, __shfl_xor(v, 2));
                        v = fmaxf(v, __shfl_xor(v, 4));
                        v = fmaxf(v, __shfl_xor(v, 8));
                        int gr = bm * 128 + wm * 64 + m * 16 + lg * 4 + reg;
                        if (li == 0 && gr < R) atomicMax(&rowmax[gr], f2u(v));
                    }
                #pragma unroll
                for (int n = 0; n < 4; ++n) {
                    float v = MASKED;
                    #pragma unroll
                    for (int m = 0; m < 4; ++m)
                        #pragma unroll
                        for (int reg = 0; reg < 4; ++reg) {
                            int gr = bm * 128 + wm * 64 + m * 16 + lg * 4 + reg;
                            v = fmaxf(v, (gr < R) ? acc[m][n][reg] : MASKED);
                        }
                    v = fmaxf(v, __shfl_xor(v, 16));
                    v = fmaxf(v, __shfl_xor(v, 32));
                    int gc = bnv * 128 + wn * 64 + n * 16 + li;
                    if (lg == 0 && gc < Fc) atomicMax(&colmax[gc], f2u(v));
                }
                #pragma unroll
                for (int m = 0; m < 4; ++m)
                    #pragma unroll
                    for (int n = 0; n < 4; ++n)
                        acc[m][n] = (f32x4){0.f, 0.f, 0.f, 0.f};
            }
        }
    }
}

// ============================================================================
// K4: maxes -> loss, masked means, scalar out.
// ============================================================================
__global__ void k_final(const u32* __restrict__ rowmax, const u32* __restrict__ colmax,
                        const int* __restrict__ meta, float* __restrict__ out)
{
    const int R = meta[0], Fc = meta[1];
    const int t = threadIdx.x;
    float sr = 0.f, sf = 0.f;
    for (int i = t; i < R; i += 256) {
        u32 u = rowmax[i];
        float m = (u == 0u) ? -1e9f : u2f(u) * INV_TEMP;
        float sg = 1.0f / (1.0f + expf(-m));
        sr += -logf(1.0f - sg + 1e-6f);
    }
    for (int i = t; i < Fc; i += 256) {
        u32 u = colmax[i];
        float m = (u == 0u) ? -1e9f : u2f(u) * INV_TEMP;
        float sg = 1.0f / (1.0f + expf(-m));
        sf += -logf(1.0f - sg + 1e-6f);
    }
    #pragma unroll
    for (int msk = 32; msk >= 1; msk >>= 1) {
        sr += __shfl_xor(sr, msk);
        sf += __shfl_xor(sf, msk);
    }
    __shared__ float r4[4], f4[4];
    if ((t & 63) == 0) { r4[t >> 6] = sr; f4[t >> 6] = sf; }
    __syncthreads();
    if (t == 0) {
        float a = (r4[0] + r4[1] + r4[2] + r4[3]) / (float)((R > 0) ? R : 1);
        float b = (f4[0] + f4[1] + f4[2] + f4[3]) / (float)((Fc > 0) ? Fc : 1);
        out[0] = 0.5f * (a + b);
    }
}

// ============================================================================
extern "C" void kernel_launch(void* const* d_in, const int* in_sizes, int n_in,
                              void* d_out, int out_size, void* d_ws, size_t ws_size,
                              hipStream_t stream)
{
    (void)in_sizes; (void)n_in; (void)out_size; (void)ws_size;
    const float* x    = (const float*)d_in[0];
    const int* labels = (const int*)d_in[1];
    float* out        = (float*)d_out;

    char* ws = (char*)d_ws;
    int* meta = (int*)ws;
    int* pos  = (int*)(ws + 256);
    __hip_bfloat16* Xall = (__hip_bfloat16*)(ws + 131072);
    u32* rowmax = (u32*)(ws + 131072 + XALL_BYTES);
    u32* colmax = rowmax + 16384;

    k_scan<<<1, 256, 0, stream>>>(labels, pos, meta);
    k_norm<<<T_TOK, 256, 0, stream>>>(x, labels, pos, meta, Xall);
    hipMemsetAsync(rowmax, 0, 2 * 16384 * sizeof(u32), stream);
    k_gemm<<<512, 256, 0, stream>>>(Xall, meta, rowmax, colmax);
    k_final<<<1, 256, 0, stream>>>(rowmax, colmax, meta, out);
}

// Round 10
// 173.041 us; speedup vs baseline: 1.0753x; 1.0084x over previous
//
#include <hip/hip_runtime.h>
#include <hip/hip_bf16.h>

// Problem constants: B=16, N=1024, D=768 -> T=16384 tokens.
#define T_TOK   16384
#define D_DIM   768
#define ROWB    1536          // bytes per row (768 * 2B bf16)
#define INV_TEMP (1.0f/0.07f)
#define XROWS   17152
#define XALL_BYTES (XROWS * ROWB)

typedef __bf16 bf16x8 __attribute__((ext_vector_type(8)));
typedef float  f32x4  __attribute__((ext_vector_type(4)));
typedef unsigned int u32;

__device__ __forceinline__ u32 f2u(float f) {
    u32 b = __float_as_uint(f);
    return (b & 0x80000000u) ? ~b : (b | 0x80000000u);
}
__device__ __forceinline__ float u2f(u32 u) {
    u32 b = (u & 0x80000000u) ? (u & 0x7FFFFFFFu) : ~u;
    return __uint_as_float(b);
}

__device__ __forceinline__ void gload16(const void* g, void* l) {
    __builtin_amdgcn_global_load_lds((const __attribute__((address_space(1))) u32*)g,
                                     (__attribute__((address_space(3))) u32*)l,
                                     16, 0, 0);
}

// ============================================================================
// K1: class-wise prefix scan. meta[0]=R, meta[1]=F, meta[2]=Rpad(256-aligned).
// ============================================================================
__global__ void k_scan(const int* __restrict__ labels, int* __restrict__ pos,
                       int* __restrict__ meta)
{
    __shared__ int sr[256], sf[256];
    const int t = threadIdx.x;
    const int base = t * 64;
    int cr = 0, cf = 0;
    for (int i = 0; i < 64; ++i) {
        int v = labels[base + i];
        cr += (v == 0);
        cf += (v == 1);
    }
    sr[t] = cr; sf[t] = cf;
    __syncthreads();
    if (t == 0) {
        int ar = 0, af = 0;
        for (int i = 0; i < 256; ++i) {
            int r = sr[i]; sr[i] = ar; ar += r;
            int f = sf[i]; sf[i] = af; af += f;
        }
        meta[0] = ar;
        meta[1] = af;
        meta[2] = (ar + 255) & ~255;
    }
    __syncthreads();
    int pr = sr[t], pf = sf[t];
    for (int i = 0; i < 64; ++i) {
        int v = labels[base + i];
        pos[base + i] = (v == 0) ? pr++ : pf++;
    }
}

// ============================================================================
// K2: L2-normalize rows, bf16-convert, scatter compacted by class.
// ============================================================================
__global__ void k_norm(const float* __restrict__ x, const int* __restrict__ labels,
                       const int* __restrict__ pos, const int* __restrict__ meta,
                       __hip_bfloat16* __restrict__ Xall)
{
    const int row = blockIdx.x;
    const int t = threadIdx.x;
    const float* xr = x + (size_t)row * D_DIM;
    float a0 = xr[t], a1 = xr[t + 256], a2 = xr[t + 512];
    float ss = a0 * a0 + a1 * a1 + a2 * a2;
    #pragma unroll
    for (int m = 32; m >= 1; m >>= 1) ss += __shfl_xor(ss, m);
    __shared__ float sred[4];
    if ((t & 63) == 0) sred[t >> 6] = ss;
    __syncthreads();
    float tot = sred[0] + sred[1] + sred[2] + sred[3];
    float inv = 1.0f / fmaxf(sqrtf(tot), 1e-12f);
    int lab = labels[row];
    int base = (lab == 0) ? pos[row] : (meta[2] + pos[row]);
    __hip_bfloat16* dst = Xall + (size_t)base * D_DIM;
    dst[t]       = __float2bfloat16(a0 * inv);
    dst[t + 256] = __float2bfloat16(a1 * inv);
    dst[t + 512] = __float2bfloat16(a2 * inv);
}

// ============================================================================
// K3 (round 10): round-7 data paths (verified passing: 128x128 tile, 4 waves
// 2x2, A+B LDS double buffer 64 KiB, 2 blocks/CU, streaming bn, XCD decode)
// with a NEW sync schedule -- T14 issue-early/wait-late, NO counted vmcnt:
//   TILE(b,t): STAGE_A(b^1,t+1); STAGE_B(b^1,t+1);   // issue at tile START
//              LOAD_A(b); LOAD_B0(b); MM(0); LOAD_B1(b); MM(2);
//              DRAIN0;                                // vmcnt(0); s_barrier
// Safety (rigorous, no counting):
//  RAW stage->read: each wave's vmcnt(0) forces its OWN stage-writes before
//    it reaches the barrier; barrier -> ALL writes land before any wave
//    reads buf^1 in tile t+1.
//  WAR read->stage: tile t's ds_reads complete before each wave's MFMA uses
//    (compiler lgkm waits), which precede its barrier arrival; next write to
//    buf b issues only after that barrier (gload_lds is a memory op -- it
//    cannot cross the "memory"-clobber DRAIN0 asm).
//  Stage latency (~900 cyc HBM worst case) hides under the full tile body;
//  1 barrier per K-tile instead of round 7's 3.
// ============================================================================
#define MFMA16(a,b,c) __builtin_amdgcn_mfma_f32_16x16x32_bf16(a,b,c,0,0,0)

#define LA(b)  (lds + (b)*32768)
#define LBr(b) (lds + (b)*32768 + 16384)

// step s -> (bi=s/12, kt=s%12); wave-uniform scalar math.
#define STAGE_A(b,s) do { \
    int kt_ = (s) % 12; \
    const char* ap_ = Ab + aoff + kt_*128; \
    gload16(ap_,           LA(b) + wq); \
    gload16(ap_ +  49152,  LA(b) + wq + 4096); \
    gload16(ap_ +  98304,  LA(b) + wq + 8192); \
    gload16(ap_ + 147456,  LA(b) + wq + 12288); } while(0)
#define STAGE_B(b,s) do { \
    int bi_ = (s)/12, kt_ = (s)%12; \
    const char* bp_ = Bb + (size_t)(grp + Gm*bi_) * (128*ROWB) + aoff + kt_*128; \
    gload16(bp_,           LBr(b) + wq); \
    gload16(bp_ +  49152,  LBr(b) + wq + 4096); \
    gload16(bp_ +  98304,  LBr(b) + wq + 8192); \
    gload16(bp_ + 147456,  LBr(b) + wq + 12288); } while(0)

#define DRAIN0 asm volatile("s_waitcnt vmcnt(0)\n\ts_barrier" ::: "memory")

#define LOAD_A(b) do { \
    _Pragma("unroll") \
    for (int mm = 0; mm < 4; ++mm) { \
        afr[mm][0] = *(const bf16x8*)(LA(b) + aBase + mm*2048 + cb0); \
        afr[mm][1] = *(const bf16x8*)(LA(b) + aBase + mm*2048 + cb1); } } while(0)
#define LOAD_B0(b) do { \
    _Pragma("unroll") \
    for (int nn = 0; nn < 2; ++nn) { \
        bfrA[nn][0] = *(const bf16x8*)(LBr(b) + bBase + nn*2048 + cb0); \
        bfrA[nn][1] = *(const bf16x8*)(LBr(b) + bBase + nn*2048 + cb1); } } while(0)
#define LOAD_B1(b) do { \
    _Pragma("unroll") \
    for (int nn = 0; nn < 2; ++nn) { \
        bfrB[nn][0] = *(const bf16x8*)(LBr(b) + bBase + (2+nn)*2048 + cb0); \
        bfrB[nn][1] = *(const bf16x8*)(LBr(b) + bBase + (2+nn)*2048 + cb1); } } while(0)

#define MM(nbase,bvx) do { \
    __builtin_amdgcn_s_setprio(1); \
    _Pragma("unroll") \
    for (int mm = 0; mm < 4; ++mm) { \
        _Pragma("unroll") \
        for (int nn = 0; nn < 2; ++nn) { \
            acc[mm][(nbase)+nn] = MFMA16(afr[mm][0], bvx[nn][0], acc[mm][(nbase)+nn]); \
            acc[mm][(nbase)+nn] = MFMA16(afr[mm][1], bvx[nn][1], acc[mm][(nbase)+nn]); } } \
    __builtin_amdgcn_s_setprio(0); \
} while(0)

#define TILE(b,t) do { \
    int s_ = (t)+1; if (s_ > NS-1) s_ = NS-1; \
    STAGE_A((b)^1, s_); \
    STAGE_B((b)^1, s_); \
    LOAD_A(b); LOAD_B0(b); \
    MM(0, bfrA); \
    LOAD_B1(b); \
    MM(2, bfrB); \
    DRAIN0; \
} while(0)

__global__ __launch_bounds__(256, 2) void k_gemm(const __hip_bfloat16* __restrict__ Xall,
                                                 const int* __restrict__ meta,
                                                 u32* __restrict__ rowmax,
                                                 u32* __restrict__ colmax)
{
    const int R = meta[0], Fc = meta[1], Rpad = meta[2];
    const int nbm = (R + 127) >> 7;
    const int nbn = (Fc + 127) >> 7;
    if (nbm == 0 || nbn == 0) return;
    const int Gm = (nbn < 8) ? nbn : 8;
    const int P  = nbm * Gm;

    __shared__ __align__(16) char lds[65536];

    const int tid = threadIdx.x;
    const int w  = tid >> 6, l = tid & 63;
    const int wm = w >> 1, wn = w & 1;
    const int lg = l >> 4, li = l & 15;
    const int wq = w * 1024;

    // staging geometry: thread covers row (tid>>3) + i*32, chunk (tid&7)^(row&7)
    const int srow = tid >> 3;
    const int ch   = ((tid & 7) ^ (srow & 7)) * 16;
    const int aoff = srow * ROWB + ch;

    const char* Bb = (const char*)Xall + (size_t)Rpad * ROWB;

    // MFMA read geometry
    const int aBase = (wm * 64 + li) * 128;
    const int bBase = (wn * 64 + li) * 128;
    const int sw  = li & 7;
    const int cb0 = (lg ^ sw) * 16;
    const int cb1 = ((4 + lg) ^ sw) * 16;

    const float MASKED = -3.0f;
    f32x4 acc[4][4];
    #pragma unroll
    for (int m = 0; m < 4; ++m)
        #pragma unroll
        for (int n = 0; n < 4; ++n)
            acc[m][n] = (f32x4){0.f, 0.f, 0.f, 0.f};

    bf16x8 afr[4][2], bfrA[2][2], bfrB[2][2];

    #pragma unroll 1
    for (int p = blockIdx.x; p < P; p += 512) {
        // ---- decode (bm, grp); XCD-clustered in the common case ----
        int bm, grp;
        if (nbm == 64 && Gm == 8) {
            int xcd = p & 7, i = p >> 3;
            bm = ((i & 7) << 3) + xcd;   // XCD x owns bm == x (mod 8)
            grp = i >> 3;
        } else {
            bm = p % nbm; grp = p / nbm;
        }
        const int nt = (nbn - grp + Gm - 1) / Gm;
        const int NS = 12 * nt;

        const char* Ab = (const char*)Xall + (size_t)(bm * 128) * ROWB;

        // prologue: tile0 A+B -> buf0; drain (also clears prior-stream vm ops)
        STAGE_A(0, 0); STAGE_B(0, 0);
        DRAIN0;

        #pragma unroll 1
        for (int th = 0; th < NS; th += 2) {
            TILE(0, th);
            TILE(1, th + 1);

            if (((th + 1) % 12) == 11) {
                // ---- per-bn register epilogue (no barriers) ----
                const int bnv = grp + Gm * ((th + 1) / 12);
                #pragma unroll
                for (int m = 0; m < 4; ++m)
                    #pragma unroll
                    for (int reg = 0; reg < 4; ++reg) {
                        float v = MASKED;
                        #pragma unroll
                        for (int n = 0; n < 4; ++n) {
                            int gc = bnv * 128 + wn * 64 + n * 16 + li;
                            v = fmaxf(v, (gc < Fc) ? acc[m][n][reg] : MASKED);
                        }
                        v = fmaxf(v, __shfl_xor(v, 1));
                        v = fmaxf(v, __shfl_xor(v, 2));
                        v = fmaxf(v, __shfl_xor(v, 4));
                        v = fmaxf(v, __shfl_xor(v, 8));
                        int gr = bm * 128 + wm * 64 + m * 16 + lg * 4 + reg;
                        if (li == 0 && gr < R) atomicMax(&rowmax[gr], f2u(v));
                    }
                #pragma unroll
                for (int n = 0; n < 4; ++n) {
                    float v = MASKED;
                    #pragma unroll
                    for (int m = 0; m < 4; ++m)
                        #pragma unroll
                        for (int reg = 0; reg < 4; ++reg) {
                            int gr = bm * 128 + wm * 64 + m * 16 + lg * 4 + reg;
                            v = fmaxf(v, (gr < R) ? acc[m][n][reg] : MASKED);
                        }
                    v = fmaxf(v, __shfl_xor(v, 16));
                    v = fmaxf(v, __shfl_xor(v, 32));
                    int gc = bnv * 128 + wn * 64 + n * 16 + li;
                    if (lg == 0 && gc < Fc) atomicMax(&colmax[gc], f2u(v));
                }
                #pragma unroll
                for (int m = 0; m < 4; ++m)
                    #pragma unroll
                    for (int n = 0; n < 4; ++n)
                        acc[m][n] = (f32x4){0.f, 0.f, 0.f, 0.f};
            }
        }
    }
}

// ============================================================================
// K4: maxes -> loss, masked means, scalar out.
// ============================================================================
__global__ void k_final(const u32* __restrict__ rowmax, const u32* __restrict__ colmax,
                        const int* __restrict__ meta, float* __restrict__ out)
{
    const int R = meta[0], Fc = meta[1];
    const int t = threadIdx.x;
    float sr = 0.f, sf = 0.f;
    for (int i = t; i < R; i += 256) {
        u32 u = rowmax[i];
        float m = (u == 0u) ? -1e9f : u2f(u) * INV_TEMP;
        float sg = 1.0f / (1.0f + expf(-m));
        sr += -logf(1.0f - sg + 1e-6f);
    }
    for (int i = t; i < Fc; i += 256) {
        u32 u = colmax[i];
        float m = (u == 0u) ? -1e9f : u2f(u) * INV_TEMP;
        float sg = 1.0f / (1.0f + expf(-m));
        sf += -logf(1.0f - sg + 1e-6f);
    }
    #pragma unroll
    for (int msk = 32; msk >= 1; msk >>= 1) {
        sr += __shfl_xor(sr, msk);
        sf += __shfl_xor(sf, msk);
    }
    __shared__ float r4[4], f4[4];
    if ((t & 63) == 0) { r4[t >> 6] = sr; f4[t >> 6] = sf; }
    __syncthreads();
    if (t == 0) {
        float a = (r4[0] + r4[1] + r4[2] + r4[3]) / (float)((R > 0) ? R : 1);
        float b = (f4[0] + f4[1] + f4[2] + f4[3]) / (float)((Fc > 0) ? Fc : 1);
        out[0] = 0.5f * (a + b);
    }
}

// ============================================================================
extern "C" void kernel_launch(void* const* d_in, const int* in_sizes, int n_in,
                              void* d_out, int out_size, void* d_ws, size_t ws_size,
                              hipStream_t stream)
{
    (void)in_sizes; (void)n_in; (void)out_size; (void)ws_size;
    const float* x    = (const float*)d_in[0];
    const int* labels = (const int*)d_in[1];
    float* out        = (float*)d_out;

    char* ws = (char*)d_ws;
    int* meta = (int*)ws;
    int* pos  = (int*)(ws + 256);
    __hip_bfloat16* Xall = (__hip_bfloat16*)(ws + 131072);
    u32* rowmax = (u32*)(ws + 131072 + XALL_BYTES);
    u32* colmax = rowmax + 16384;

    k_scan<<<1, 256, 0, stream>>>(labels, pos, meta);
    k_norm<<<T_TOK, 256, 0, stream>>>(x, labels, pos, meta, Xall);
    hipMemsetAsync(rowmax, 0, 2 * 16384 * sizeof(u32), stream);
    k_gemm<<<512, 256, 0, stream>>>(Xall, meta, rowmax, colmax);
    k_final<<<1, 256, 0, stream>>>(rowmax, colmax, meta, out);
}